// Round 15
// baseline (116.647 us; speedup 1.0000x reference)
//
#include <hip/hip_runtime.h>

#define SEQ 200
#define HID 64
#define BT  4
#define NBLK (4096 / BT)   // 1024 blocks -> target 4 per CU, 4 waves/SIMD

typedef _Float16 f16;
typedef _Float16 f16x8 __attribute__((ext_vector_type(8)));
typedef float    f32x4 __attribute__((ext_vector_type(4)));

#define LOG2E 1.44269504088896340736f

#if __has_builtin(__builtin_amdgcn_exp2f)
#define EXP2F(x) __builtin_amdgcn_exp2f(x)
#else
#define EXP2F(x) __expf(0.69314718056f * (x))
#endif
#define RCPF(x) __builtin_amdgcn_rcpf(x)

// v15 = R13's sigma(R)=R>>2 mapping with R13's four mistakes fixed:
//  - fragment row R holds batch R>>2; only rows {0,4,8,12} are real (they feed
//    the consumed C-rows 4a); rows 4a+1..3 feed discarded C-rows and stay 0.
//  - lane group a reads its single cell (b=a, j=jpw) STATICALLY from
//    acc[q][0] (no runtime vector index, no merge, 64/64 lanes active).
//  - C-init: ini[0..3] = x_a*wih + bias broadcast (discarded rows tolerate
//    garbage-finite) -> 1 x-read + 1 fmaf.
//  - W_lin staged as f16 in LDS (25.6 KB): no in-loop VMEM -> no vmcnt drain
//    at the barrier; block LDS ~33 KB -> 4 blocks/CU.
//  - single h-write (row 4a); shared-rcp trans (5 exp + 3 rcp per cell);
//    launch_bounds(256,2) to avoid R13's AGPR trap (VGPR cap 128 broke into
//    accvgpr shuffling at (256,4); natural use ~85 keeps 4 blocks resident).
__global__ __launch_bounds__(256, 2)
void qlstm_v15(const float* __restrict__ x,      // [4096, 200]
               const float* __restrict__ W_ih,   // [256]
               const float* __restrict__ W_hh,   // [256, 64]
               const float* __restrict__ b_ih,   // [256]
               const float* __restrict__ b_hh,   // [256]
               const float* __restrict__ W_lin,  // [200*64]
               const float* __restrict__ b_lin,  // [1]
               float* __restrict__ out)          // [4096]
{
    __shared__ float x_lds[BT][201];        // 3.2 KB
    __shared__ f16   h_frag[2][16 * HID];   // 4 KB dbuf, swizzled frag layout
    __shared__ f16   wl16[SEQ * HID];       // 25.6 KB (f16 W_lin)
    __shared__ float out_part[4][BT];

    const int tid = threadIdx.x;
    const int w   = tid >> 6;     // wave: j-block owner
    const int l   = tid & 63;
    const int m   = l & 15;       // B col / C col
    const int a   = l >> 4;       // k-group / C row-group = this lane's batch row
    const int b0  = blockIdx.x * BT;

    // quadrant pre-scales: i,f,o -> log2e ; g -> 2*log2e
    const float qs[4] = {LOG2E, LOG2E, 2.0f * LOG2E, LOG2E};

    // ---- stage x rows 0..3 (f32, coalesced) ----
    for (int i = tid; i < BT * SEQ; i += 256) {
        int b = i / SEQ, t = i - b * SEQ;
        x_lds[b][t] = x[(size_t)b0 * SEQ + i];
    }
    // ---- stage W_lin as f16 (float2 source reads) ----
    {
        const float2* src = (const float2*)W_lin;
        for (int i = tid; i < SEQ * HID / 2; i += 256) {
            float2 v = src[i];
            wl16[2 * i]     = (f16)v.x;
            wl16[2 * i + 1] = (f16)v.y;
        }
    }
    // ---- zero both h buffers (rows != 0 mod 4 stay zero forever) ----
    for (int i = tid; i < 1024; i += 256) ((float*)h_frag)[i] = 0.0f;

    // ---- B fragments (W_hh^T, pre-scaled) once: col n=q*64+16w+m, k=kk*32+a*8+e ----
    f16x8 Bf[4][2];
    float wihq[4], biasq[4];
    #pragma unroll
    for (int q = 0; q < 4; ++q) {
        const int n = q * 64 + w * 16 + m;
        wihq[q]  = W_ih[n] * qs[q];
        biasq[q] = (b_ih[n] + b_hh[n]) * qs[q];
        #pragma unroll
        for (int kk = 0; kk < 2; ++kk) {
            const float4* p = (const float4*)(W_hh + n * HID + kk * 32 + a * 8);
            float4 lo = p[0], hi = p[1];
            f16x8 f;
            f[0] = (f16)(lo.x * qs[q]); f[1] = (f16)(lo.y * qs[q]);
            f[2] = (f16)(lo.z * qs[q]); f[3] = (f16)(lo.w * qs[q]);
            f[4] = (f16)(hi.x * qs[q]); f[5] = (f16)(hi.y * qs[q]);
            f[6] = (f16)(hi.z * qs[q]); f[7] = (f16)(hi.w * qs[q]);
            Bf[q][kk] = f;
        }
    }

    const int jpw = w * 16 + m;
    // A-frag read addrs: row m, slot s=kk*4+a, byte = m*128 + ((s^(m&7))<<4)
    const int ra0 = m * 128 + (((0 + a) ^ (m & 7)) << 4);
    const int ra1 = m * 128 + (((4 + a) ^ (m & 7)) << 4);
    // h write addr: batch a -> fragment row R0 = 4a only.
    // byte(R, j) = R*128 + (((j>>3) ^ (R&7))<<4) + (j&7)*2
    const int R0 = 4 * a;
    const int hw = R0 * 128 + (((jpw >> 3) ^ (R0 & 7)) << 4) + (jpw & 7) * 2;

    const char* hbytes = (const char*)h_frag;

    float c = 0.0f, o = 0.0f;
    const float t2s = 2.0f * LOG2E;

    __syncthreads();

    for (int t = 0; t < SEQ; ++t) {
        const int rb = (t & 1) << 11;   // read-buffer byte offset
        const int wb = rb ^ 2048;       // write-buffer byte offset

        // ======== gate GEMM (C-in broadcast; consumed C-row = 4a) ========
        __builtin_amdgcn_s_setprio(1);
        const f16x8 A0 = *(const f16x8*)(hbytes + rb + ra0);
        const f16x8 A1 = *(const f16x8*)(hbytes + rb + ra1);
        const float xv = x_lds[a][t];
        const float wl = (float)wl16[t * HID + jpw];

        f32x4 acc[4];
        #pragma unroll
        for (int q = 0; q < 4; ++q) {
            const float i0 = fmaf(xv, wihq[q], biasq[q]);
            f32x4 ini;
            ini[0] = i0; ini[1] = i0; ini[2] = i0; ini[3] = i0;
            f32x4 z = __builtin_amdgcn_mfma_f32_16x16x32_f16(A0, Bf[q][0], ini, 0, 0, 0);
            acc[q]  = __builtin_amdgcn_mfma_f32_16x16x32_f16(A1, Bf[q][1], z, 0, 0, 0);
        }
        __builtin_amdgcn_s_setprio(0);

        // ======== pointwise: ONE cell per lane (b=a, j=jpw), shared-rcp ========
        const float eA = EXP2F(-acc[0][0]);
        const float eC = EXP2F(-acc[1][0]);
        const float eB = EXP2F(acc[2][0]);
        const float eE = EXP2F(-acc[3][0]);
        const float ig = (eB - 1.0f) * RCPF((1.0f + eA) * (eB + 1.0f));
        const float gf = RCPF(1.0f + eC);
        c = fmaf(gf, c, t2s * ig);           // c pre-scaled by 2*log2e
        const float eD = EXP2F(c);
        const float h  = (eD - 1.0f) * RCPF((1.0f + eE) * (eD + 1.0f));
        *(f16*)((char*)h_frag + wb + hw) = (f16)h;
        o = fmaf(h, wl, o);

        __syncthreads();   // h(write-buf) complete -> next step reads it
    }

    // ---- reduce over j: 16 lanes (m) in-wave, then 4 waves via LDS ----
    float v = o;
    #pragma unroll
    for (int off = 1; off < 16; off <<= 1)
        v += __shfl_xor(v, off, 64);
    if (m == 0) out_part[w][a] = v;
    __syncthreads();
    if (tid < BT) {
        out[b0 + tid] = out_part[0][tid] + out_part[1][tid]
                      + out_part[2][tid] + out_part[3][tid] + b_lin[0];
    }
}

extern "C" void kernel_launch(void* const* d_in, const int* in_sizes, int n_in,
                              void* d_out, int out_size, void* d_ws, size_t ws_size,
                              hipStream_t stream) {
    const float* x     = (const float*)d_in[0];
    const float* W_ih  = (const float*)d_in[1];
    const float* W_hh  = (const float*)d_in[2];
    const float* b_ih  = (const float*)d_in[3];
    const float* b_hh  = (const float*)d_in[4];
    const float* W_lin = (const float*)d_in[5];
    const float* b_lin = (const float*)d_in[6];
    float* out = (float*)d_out;

    dim3 grid(NBLK);
    dim3 block(256);
    qlstm_v15<<<grid, block, 0, stream>>>(x, W_ih, W_hh, b_ih, b_hh,
                                          W_lin, b_lin, out);
}

// Round 16
// 101.399 us; speedup vs baseline: 1.1504x; 1.1504x over previous
//
#include <hip/hip_runtime.h>

#define SEQ 200
#define HID 64
#define BT  8
#define NBLK (4096 / BT)   // 512 blocks -> 2 per CU, 2 waves/SIMD

typedef _Float16 f16;
typedef _Float16 f16x8 __attribute__((ext_vector_type(8)));
typedef float    f32x4 __attribute__((ext_vector_type(4)));

#define LOG2E 1.44269504088896340736f

#if __has_builtin(__builtin_amdgcn_exp2f)
#define EXP2F(x) __builtin_amdgcn_exp2f(x)
#else
#define EXP2F(x) __expf(0.69314718056f * (x))
#endif
#define RCPF(x) __builtin_amdgcn_rcpf(x)

// R14 (proven, 84.5us) + serial-chain cuts:
//  1. Dechained K-reduction: accA = mfma(A0,B0,ini), accB = mfma(A1,B1,0) --
//     8 independent MFMAs + 8 v_add for the two consumed C-rows, removing one
//     MFMA latency from the post-barrier critical path.
//  2. x/W_lin for step t+1 prefetched BEFORE the barrier (read-only LDS, no
//     dependence on the h exchange); ini fmafs computed pre-barrier. Post-
//     barrier path starts directly at the A-frag ds_reads.
//     (Scalar row-major reads as R14 -- NOT R10's time-major/float2 set.)
//  3. Everything else identical to R14: sigma-row mapping (frag row r holds
//     batch 2*(r>>2)+(r&1); lane group a reads cells (2a,j),(2a+1,j) from C
//     regs 0,1), shared-rcp trans (5 exp + 3 rcp/cell), single h-write per
//     cell (rows 4a, 4a+1; rows 4a+2,3 stay zero), setprio around MFMA,
//     one barrier/step, XOR-swizzled dbuf h.
__global__ __launch_bounds__(256, 2)
void qlstm_v16(const float* __restrict__ x,      // [4096, 200]
               const float* __restrict__ W_ih,   // [256]
               const float* __restrict__ W_hh,   // [256, 64]
               const float* __restrict__ b_ih,   // [256]
               const float* __restrict__ b_hh,   // [256]
               const float* __restrict__ W_lin,  // [200*64]
               const float* __restrict__ b_lin,  // [1]
               float* __restrict__ out)          // [4096]
{
    __shared__ float x_lds[BT][201];        // 6.3 KB
    __shared__ f16   h_frag[2][16 * HID];   // 4 KB dbuf, swizzled frag layout
    __shared__ float wl_lds[SEQ * HID];     // 51.2 KB
    __shared__ float out_part[4][BT];

    const int tid = threadIdx.x;
    const int w   = tid >> 6;     // wave: j-block owner
    const int l   = tid & 63;
    const int m   = l & 15;       // B col / C col
    const int a   = l >> 4;       // k-group / C row-group
    const int b0  = blockIdx.x * BT;

    // quadrant pre-scales: i,f,o -> log2e ; g -> 2*log2e
    const float qs[4] = {LOG2E, LOG2E, 2.0f * LOG2E, LOG2E};

    // ---- stage x rows 0..7 (f32, coalesced) ----
    for (int i = tid; i < BT * SEQ; i += 256) {
        int b = i / SEQ, t = i - b * SEQ;
        x_lds[b][t] = x[(size_t)b0 * SEQ + i];
    }
    // ---- stage W_lin (float4) ----
    {
        const float4* src = (const float4*)W_lin;
        float4* dst = (float4*)wl_lds;
        for (int i = tid; i < SEQ * HID / 4; i += 256) dst[i] = src[i];
    }
    // ---- zero both h buffers (rows == 2,3 mod 4 stay zero forever) ----
    for (int i = tid; i < 1024; i += 256) ((float*)h_frag)[i] = 0.0f;

    // ---- B fragments (W_hh^T, pre-scaled) once: col n=q*64+16w+m, k=kk*32+a*8+e ----
    f16x8 Bf[4][2];
    float wihq[4], biasq[4];
    #pragma unroll
    for (int q = 0; q < 4; ++q) {
        const int n = q * 64 + w * 16 + m;
        wihq[q]  = W_ih[n] * qs[q];
        biasq[q] = (b_ih[n] + b_hh[n]) * qs[q];
        #pragma unroll
        for (int kk = 0; kk < 2; ++kk) {
            const float4* p = (const float4*)(W_hh + n * HID + kk * 32 + a * 8);
            float4 lo = p[0], hi = p[1];
            f16x8 f;
            f[0] = (f16)(lo.x * qs[q]); f[1] = (f16)(lo.y * qs[q]);
            f[2] = (f16)(lo.z * qs[q]); f[3] = (f16)(lo.w * qs[q]);
            f[4] = (f16)(hi.x * qs[q]); f[5] = (f16)(hi.y * qs[q]);
            f[6] = (f16)(hi.z * qs[q]); f[7] = (f16)(hi.w * qs[q]);
            Bf[q][kk] = f;
        }
    }

    const int jpw = w * 16 + m;
    // A-frag read addrs: row m, slot s=kk*4+a, byte = m*128 + ((s^(m&7))<<4)
    const int ra0 = m * 128 + (((0 + a) ^ (m & 7)) << 4);
    const int ra1 = m * 128 + (((4 + a) ^ (m & 7)) << 4);
    // this lane's two batch rows (direct from C regs 0,1 -- no merge)
    const int bA = 2 * a;
    const int bB = 2 * a + 1;
    // h write addrs: ONLY rows 4a (batch bA) and 4a+1 (batch bB) are consumed.
    const int R0 = 4 * a, R1 = 4 * a + 1;
    const int hwA = R0 * 128 + (((jpw >> 3) ^ (R0 & 7)) << 4) + (jpw & 7) * 2;
    const int hwB = R1 * 128 + (((jpw >> 3) ^ (R1 & 7)) << 4) + (jpw & 7) * 2;

    const char* hbytes = (const char*)h_frag;

    float cA = 0.0f, cB = 0.0f, oA = 0.0f, oB = 0.0f;
    const float t2s = 2.0f * LOG2E;
    const f32x4 zz = {0.f, 0.f, 0.f, 0.f};

    // ---- prefetch step-0 x / W_lin (read-only LDS; independent of h) ----
    float x0n = 0.f, x1n = 0.f, wln = 0.f;

    __syncthreads();
    x0n = x_lds[bA][0];
    x1n = x_lds[bB][0];
    wln = wl_lds[jpw];

    for (int t = 0; t < SEQ; ++t) {
        const int rb = (t & 1) << 11;   // read-buffer byte offset
        const int wb = rb ^ 2048;       // write-buffer byte offset

        const float x0 = x0n, x1 = x1n, wl = wln;
        // ini fmafs use only prefetched regs -- schedulable pre-A-read
        float i0[4], i1[4];
        #pragma unroll
        for (int q = 0; q < 4; ++q) {
            i0[q] = fmaf(x0, wihq[q], biasq[q]);
            i1[q] = fmaf(x1, wihq[q], biasq[q]);
        }

        // ======== gate GEMM: 8 INDEPENDENT MFMAs ========
        __builtin_amdgcn_s_setprio(1);
        const f16x8 A0 = *(const f16x8*)(hbytes + rb + ra0);
        const f16x8 A1 = *(const f16x8*)(hbytes + rb + ra1);

        f32x4 accA[4], accB[4];
        #pragma unroll
        for (int q = 0; q < 4; ++q) {
            f32x4 ini;
            ini[0] = i0[q]; ini[1] = i1[q]; ini[2] = i0[q]; ini[3] = i1[q];
            accA[q] = __builtin_amdgcn_mfma_f32_16x16x32_f16(A0, Bf[q][0], ini, 0, 0, 0);
            accB[q] = __builtin_amdgcn_mfma_f32_16x16x32_f16(A1, Bf[q][1], zz, 0, 0, 0);
        }
        __builtin_amdgcn_s_setprio(0);

        // ---- prefetch next step's x / W_lin (read-only LDS regions) ----
        {
            int tn = t + 1; if (tn == SEQ) tn = 0;   // uniform, scalar select
            x0n = x_lds[bA][tn];
            x1n = x_lds[bB][tn];
            wln = wl_lds[tn * HID + jpw];
        }

        // ---- merge the two consumed C-rows (8 v_add) ----
        const float gA0 = accA[0][0] + accB[0][0];
        const float gA1 = accA[1][0] + accB[1][0];
        const float gA2 = accA[2][0] + accB[2][0];
        const float gA3 = accA[3][0] + accB[3][0];
        const float gB0 = accA[0][1] + accB[0][1];
        const float gB1 = accA[1][1] + accB[1][1];
        const float gB2 = accA[2][1] + accB[2][1];
        const float gB3 = accA[3][1] + accB[3][1];

        // ======== pointwise: two cells per thread, shared-rcp trans ========
        {
            const float eA = EXP2F(-gA0);
            const float eC = EXP2F(-gA1);
            const float eB = EXP2F(gA2);
            const float eE = EXP2F(-gA3);
            const float ig = (eB - 1.0f) * RCPF((1.0f + eA) * (eB + 1.0f));
            const float gf = RCPF(1.0f + eC);
            cA = fmaf(gf, cA, t2s * ig);          // cA pre-scaled by 2*log2e
            const float eD = EXP2F(cA);
            const float h  = (eD - 1.0f) * RCPF((1.0f + eE) * (eD + 1.0f));
            *(f16*)((char*)h_frag + wb + hwA) = (f16)h;
            oA = fmaf(h, wl, oA);
        }
        {
            const float eA = EXP2F(-gB0);
            const float eC = EXP2F(-gB1);
            const float eB = EXP2F(gB2);
            const float eE = EXP2F(-gB3);
            const float ig = (eB - 1.0f) * RCPF((1.0f + eA) * (eB + 1.0f));
            const float gf = RCPF(1.0f + eC);
            cB = fmaf(gf, cB, t2s * ig);
            const float eD = EXP2F(cB);
            const float h  = (eD - 1.0f) * RCPF((1.0f + eE) * (eD + 1.0f));
            *(f16*)((char*)h_frag + wb + hwB) = (f16)h;
            oB = fmaf(h, wl, oB);
        }

        __syncthreads();   // h(write-buf) complete -> next step reads it
    }

    // ---- reduce over j: 16 lanes (m) in-wave, then 4 waves via LDS ----
    float vA = oA, vB = oB;
    #pragma unroll
    for (int off = 1; off < 16; off <<= 1) {
        vA += __shfl_xor(vA, off, 64);
        vB += __shfl_xor(vB, off, 64);
    }
    if (m == 0) {
        out_part[w][bA] = vA;
        out_part[w][bB] = vB;
    }
    __syncthreads();
    if (tid < BT) {
        out[b0 + tid] = out_part[0][tid] + out_part[1][tid]
                      + out_part[2][tid] + out_part[3][tid] + b_lin[0];
    }
}

extern "C" void kernel_launch(void* const* d_in, const int* in_sizes, int n_in,
                              void* d_out, int out_size, void* d_ws, size_t ws_size,
                              hipStream_t stream) {
    const float* x     = (const float*)d_in[0];
    const float* W_ih  = (const float*)d_in[1];
    const float* W_hh  = (const float*)d_in[2];
    const float* b_ih  = (const float*)d_in[3];
    const float* b_hh  = (const float*)d_in[4];
    const float* W_lin = (const float*)d_in[5];
    const float* b_lin = (const float*)d_in[6];
    float* out = (float*)d_out;

    dim3 grid(NBLK);
    dim3 block(256);
    qlstm_v16<<<grid, block, 0, stream>>>(x, W_ih, W_hh, b_ih, b_hh,
                                          W_lin, b_lin, out);
}